// Round 5
// baseline (543.939 us; speedup 1.0000x reference)
//
#include <hip/hip_runtime.h>

#define B_SZ 16384
#define NN 7
#define HID 256
#define COMB 2048

typedef __attribute__((ext_vector_type(8))) short short8;
typedef __attribute__((ext_vector_type(4))) float floatx4;
typedef __attribute__((ext_vector_type(4))) unsigned short ushortx4;
typedef unsigned short us;

__device__ __forceinline__ float bf2f(us u) {
    union { unsigned int i; float f; } v; v.i = ((unsigned int)u) << 16; return v.f;
}
__device__ __forceinline__ us f2bf(float f) {  // RNE
    union { unsigned int i; float f; } v; v.f = f;
    return (us)((v.i + 0x7FFFu + ((v.i >> 16) & 1u)) >> 16);
}
__device__ __forceinline__ us f2bf_fast(float f) {  // round-half-up (hot path)
    union { unsigned int i; float f; } v; v.f = f;
    return (us)((v.i + 0x8000u) >> 16);
}

// Pack W1 (131072), W2 (65536), wh1_w (65536), rh1_w (32768) fp32 -> contiguous bf16 dst.
__global__ __launch_bounds__(256) void pack_weights(const float* __restrict__ W1,
                                                    const float* __restrict__ W2,
                                                    const float* __restrict__ wh1,
                                                    const float* __restrict__ rh1,
                                                    us* __restrict__ dst) {
    int i = (blockIdx.x * 256 + threadIdx.x) * 4;
    if (i >= 294912) return;
    const float* src; int off;
    if (i < 131072)      { src = W1;  off = i; }
    else if (i < 196608) { src = W2;  off = i - 131072; }
    else if (i < 262144) { src = wh1; off = i - 196608; }
    else                 { src = rh1; off = i - 262144; }
    floatx4 v = *(const floatx4*)(src + off);
    ushortx4 o = {f2bf(v[0]), f2bf(v[1]), f2bf(v[2]), f2bf(v[3])};
    *(ushortx4*)(dst + i) = o;
}

// GAT attention for ONE graph by one wave (verified r2-r4 structure). In-place safe:
// reads all of h into registers before writing dst.
template <int SRC_STRIDE, bool WRITE_ALPHA>
__device__ __forceinline__ void attn_graph(const us* hb, const float* adjs, const float* avec,
                                           us* dst, int dstStride, float* alpha_dst, int lane) {
    float hv[NN][4];
#pragma unroll
    for (int n = 0; n < NN; ++n) {
        ushortx4 r = *(const ushortx4*)(hb + n * SRC_STRIDE + lane * 4);
        hv[n][0] = bf2f(r[0]); hv[n][1] = bf2f(r[1]);
        hv[n][2] = bf2f(r[2]); hv[n][3] = bf2f(r[3]);
    }
    floatx4 ai = *(const floatx4*)(avec + lane * 4);
    floatx4 aj = *(const floatx4*)(avec + HID + lane * 4);
    float si[NN], sj[NN];
#pragma unroll
    for (int n = 0; n < NN; ++n) {
        float pi = hv[n][0] * ai[0] + hv[n][1] * ai[1] + hv[n][2] * ai[2] + hv[n][3] * ai[3];
        float pj = hv[n][0] * aj[0] + hv[n][1] * aj[1] + hv[n][2] * aj[2] + hv[n][3] * aj[3];
#pragma unroll
        for (int off = 32; off; off >>= 1) {
            pi += __shfl_xor(pi, off);
            pj += __shfl_xor(pj, off);
        }
        si[n] = pi; sj[n] = pj;
    }
    const int j = lane & 7;
    float sjm = sj[0];
    if (j == 1) sjm = sj[1];
    if (j == 2) sjm = sj[2];
    if (j == 3) sjm = sj[3];
    if (j == 4) sjm = sj[4];
    if (j == 5) sjm = sj[5];
    if (j == 6) sjm = sj[6];
    const int jc = (j < 7) ? j : 0;
    float alpha[NN];
#pragma unroll
    for (int i = 0; i < NN; ++i) {
        float x = si[i] + sjm;
        x = (x >= 0.f) ? x : 0.2f * x;                     // leaky_relu 0.2
        bool ok = (j < 7) && (adjs[i * 7 + jc] != 0.f);    // adj mask + dummy col
        float e = ok ? x : -1e30f;
        float m = e;
        m = fmaxf(m, __shfl_xor(m, 1, 8));
        m = fmaxf(m, __shfl_xor(m, 2, 8));
        m = fmaxf(m, __shfl_xor(m, 4, 8));
        float ex = ok ? __expf(e - m) : 0.f;
        float s = ex;
        s += __shfl_xor(s, 1, 8);
        s += __shfl_xor(s, 2, 8);
        s += __shfl_xor(s, 4, 8);
        alpha[i] = (s > 0.f) ? ex * __frcp_rn(s) : 0.f;    // nan_to_num path
    }
    if (WRITE_ALPHA && lane < 7) {
#pragma unroll
        for (int i = 0; i < NN; ++i) alpha_dst[i * NN + lane] = alpha[i];
    }
#pragma unroll
    for (int i = 0; i < NN; ++i) {
        floatx4 o = (floatx4){0.f, 0.f, 0.f, 0.f};
#pragma unroll
        for (int jj = 0; jj < NN; ++jj) {
            float a = __shfl(alpha[i], jj, 8);
            o[0] += a * hv[jj][0]; o[1] += a * hv[jj][1];
            o[2] += a * hv[jj][2]; o[3] += a * hv[jj][3];
        }
        ushortx4 st = {f2bf(fmaxf(o[0], 0.f)), f2bf(fmaxf(o[1], 0.f)),
                       f2bf(fmaxf(o[2], 0.f)), f2bf(fmaxf(o[3], 0.f))};
        *(ushortx4*)(dst + i * dstStride + lane * 4) = st;   // relu
    }
}

// ============ single fused kernel: GEMM1+attn1+GEMM2+attn2+head+finalize ============
// 2048 blocks x 512 threads; block = 8 graphs = 56 rows (MFMA tiles padded to 64).
// LDS ~50.8 KB -> 3 blocks/CU (24 waves/CU). x2 never leaves LDS; h2 held in regs
// across the read/write hazard barrier. B-matrices read per-wave from L2 (no LDS).
__global__ __launch_bounds__(512, 6) void fused_all(const float* __restrict__ Af,
                                                    const us* __restrict__ W1b,
                                                    const us* __restrict__ W2b,
                                                    const us* __restrict__ Whb,
                                                    const float* __restrict__ adj,
                                                    const float* __restrict__ a1,
                                                    const float* __restrict__ a2,
                                                    const float* __restrict__ context,
                                                    const float* __restrict__ wh1_b,
                                                    const float* __restrict__ wh2_w,
                                                    const float* __restrict__ wh2_b,
                                                    const float* __restrict__ wh3_w,
                                                    const float* __restrict__ wh3_b,
                                                    const float* __restrict__ rh1_b,
                                                    const float* __restrict__ rh2_w,
                                                    const float* __restrict__ rh2_b,
                                                    const float* __restrict__ base_preds,
                                                    float* __restrict__ out) {
    // region0 [0,13824): As (GEMM1 staging) overlaid with red+fin (tail)
    __shared__ __attribute__((aligned(16))) char smem[52036];
    us* As = (us*)smem;                        // 64x64k chunk-major bf16 : 8192 B
    float* red = (float*)smem;                 // 8 x 384 f32             : 12288 B
    float* fin = (float*)(smem + 12288);       // 384 f32                 : 1536 B
    us* hs = (us*)(smem + 13824);              // 64 x 264 bf16           : 33792 B
    us* ctxs = (us*)(smem + 47616);            // 8 x 264 bf16            : 4224 B
    float* adjs = (float*)(smem + 51840);      // 49 f32

    const int tid = threadIdx.x;
    const int wave = tid >> 6, lane = tid & 63;
    const int quad = lane >> 4, m16 = lane & 15;
    const long rowBase = (long)blockIdx.x * 56;
    const long gbase = (long)blockIdx.x * 8;
    if (tid < 49) adjs[tid] = adj[tid];
    {   // stage context: 8 rows x 256 fp32 -> bf16 (stride 264)
        int cr = tid >> 6, c4 = (tid & 63) * 4;
        floatx4 cv = *(const floatx4*)(context + (gbase + cr) * 256 + c4);
        ushortx4 st = {f2bf(cv[0]), f2bf(cv[1]), f2bf(cv[2]), f2bf(cv[3])};
        *(ushortx4*)&ctxs[cr * 264 + c4] = st;
    }

    // ---------------- GEMM1: h1 = node_feats @ W1^T ----------------
    floatx4 acc[4][2];
#pragma unroll
    for (int rt = 0; rt < 4; ++rt)
#pragma unroll
        for (int ct = 0; ct < 2; ++ct) acc[rt][ct] = (floatx4){0.f, 0.f, 0.f, 0.f};

    const int r = tid >> 3, kq8 = tid & 7;
    long rowA = rowBase + r; if (rowA > 114687) rowA = 114687;   // tail clamp
    const float* aptr = Af + rowA * 512 + kq8 * 8;
    us* wdst = &As[((r >> 3) * 64 + (r & 7) * 8 + kq8) * 8];
    const int colb = wave * 32;

    for (int s = 0; s < 8; ++s) {
        const int k0 = s * 64;
        floatx4 v0 = *(const floatx4*)(aptr + k0);
        floatx4 v1 = *(const floatx4*)(aptr + k0 + 4);
        short8 sv;
        sv[0] = f2bf_fast(v0[0]); sv[1] = f2bf_fast(v0[1]);
        sv[2] = f2bf_fast(v0[2]); sv[3] = f2bf_fast(v0[3]);
        sv[4] = f2bf_fast(v1[0]); sv[5] = f2bf_fast(v1[1]);
        sv[6] = f2bf_fast(v1[2]); sv[7] = f2bf_fast(v1[3]);
        *(short8*)wdst = sv;
        __syncthreads();
#pragma unroll
        for (int t = 0; t < 2; ++t) {
            short8 b0 = *(const short8*)(W1b + (long)(colb + m16) * 512 + k0 + t * 32 + quad * 8);
            short8 b1 = *(const short8*)(W1b + (long)(colb + 16 + m16) * 512 + k0 + t * 32 + quad * 8);
            short8 a[4];
#pragma unroll
            for (int rt = 0; rt < 4; ++rt)
                a[rt] = *(const short8*)&As[((rt * 2 + (m16 >> 3)) * 64 + (m16 & 7) * 8 + t * 4 + quad) * 8];
#pragma unroll
            for (int rt = 0; rt < 4; ++rt) {
                acc[rt][0] = __builtin_amdgcn_mfma_f32_16x16x32_bf16(a[rt], b0, acc[rt][0], 0, 0, 0);
                acc[rt][1] = __builtin_amdgcn_mfma_f32_16x16x32_bf16(a[rt], b1, acc[rt][1], 0, 0, 0);
            }
        }
        __syncthreads();
    }
    // h1 pre-relu -> hs (rows < 56). C-layout: row = quad*4+i, col = m16.
#pragma unroll
    for (int rt = 0; rt < 4; ++rt)
#pragma unroll
        for (int ct = 0; ct < 2; ++ct)
#pragma unroll
            for (int i = 0; i < 4; ++i) {
                int row = rt * 16 + quad * 4 + i;
                if (row < 56) hs[row * 264 + wave * 32 + ct * 16 + m16] = f2bf(acc[rt][ct][i]);
            }
    __syncthreads();

    // ---------------- attention 1 (in-place: hs -> x2) ----------------
    attn_graph<264, false>(&hs[wave * 7 * 264], adjs, a1, &hs[wave * 7 * 264], 264, nullptr, lane);
    __syncthreads();

    // ---------------- GEMM2: h2 = x2 @ W2^T (A straight from hs; no barriers) ----------------
#pragma unroll
    for (int rt = 0; rt < 4; ++rt)
#pragma unroll
        for (int ct = 0; ct < 2; ++ct) acc[rt][ct] = (floatx4){0.f, 0.f, 0.f, 0.f};
#pragma unroll
    for (int ks = 0; ks < 8; ++ks) {
        const int kk = ks * 32;
        short8 b0 = *(const short8*)(W2b + (long)(colb + m16) * 256 + kk + quad * 8);
        short8 b1 = *(const short8*)(W2b + (long)(colb + 16 + m16) * 256 + kk + quad * 8);
        short8 a[4];
#pragma unroll
        for (int rt = 0; rt < 4; ++rt)
            a[rt] = *(const short8*)&hs[(rt * 16 + m16) * 264 + kk + quad * 8];
#pragma unroll
        for (int rt = 0; rt < 4; ++rt) {
            acc[rt][0] = __builtin_amdgcn_mfma_f32_16x16x32_bf16(a[rt], b0, acc[rt][0], 0, 0, 0);
            acc[rt][1] = __builtin_amdgcn_mfma_f32_16x16x32_bf16(a[rt], b1, acc[rt][1], 0, 0, 0);
        }
    }
    __syncthreads();   // all waves done READING hs before overwrite
#pragma unroll
    for (int rt = 0; rt < 4; ++rt)
#pragma unroll
        for (int ct = 0; ct < 2; ++ct)
#pragma unroll
            for (int i = 0; i < 4; ++i) {
                int row = rt * 16 + quad * 4 + i;
                if (row < 56) hs[row * 264 + wave * 32 + ct * 16 + m16] = f2bf(acc[rt][ct][i]);
            }
    __syncthreads();

    // ---------------- attention 2 (in-place; alpha -> out) ----------------
    float* alf = out + 6 * B_SZ;
    attn_graph<264, true>(&hs[wave * 7 * 264], adjs, a2, &hs[wave * 7 * 264], 264,
                          alf + (gbase + wave) * 49, lane);
    __syncthreads();

    // ---------------- head GEMM: 8 graphs x 48, K=2048 split across 8 waves ----------------
    floatx4 acc3[3];
#pragma unroll
    for (int ct = 0; ct < 3; ++ct) acc3[ct] = (floatx4){0.f, 0.f, 0.f, 0.f};
    const int g = m16 & 7;
#pragma unroll
    for (int s2 = 0; s2 < 8; ++s2) {
        const int kk = s2 * 32;
        short8 a;
        if (wave < 7) a = *(const short8*)&hs[(g * 7 + wave) * 264 + kk + quad * 8];
        else          a = *(const short8*)&ctxs[g * 264 + kk + quad * 8];
#pragma unroll
        for (int ct = 0; ct < 3; ++ct) {
            short8 bh = *(const short8*)(Whb + (long)(ct * 16 + m16) * COMB + wave * 256 + kk + quad * 8);
            acc3[ct] = __builtin_amdgcn_mfma_f32_16x16x32_bf16(a, bh, acc3[ct], 0, 0, 0);
        }
    }
    __syncthreads();   // hs reads done; red overlays As region (dead since GEMM1)
#pragma unroll
    for (int ct = 0; ct < 3; ++ct)
#pragma unroll
        for (int i = 0; i < 4; ++i) {
            int g2 = quad * 4 + i;                 // C row = graph
            if (g2 < 8) red[wave * 384 + g2 * 48 + ct * 16 + m16] = acc3[ct][i];
        }
    __syncthreads();
    if (tid < 384) {
        float ssum = 0.f;
#pragma unroll
        for (int w = 0; w < 8; ++w) ssum += red[w * 384 + tid];
        fin[tid] = ssum;
    }
    __syncthreads();
    if (tid < 8) {  // finalize MLPs, one thread per graph
        const long b = gbase + tid;
        const float* g48 = &fin[tid * 48];
        float t1[32], r1[16];
#pragma unroll
        for (int k = 0; k < 32; ++k) t1[k] = fmaxf(g48[k] + wh1_b[k], 0.f);
#pragma unroll
        for (int k = 0; k < 16; ++k) r1[k] = tanhf(g48[32 + k] + rh1_b[k]);
        float t2[16];
#pragma unroll
        for (int jj = 0; jj < 16; ++jj) {
            float s = wh2_b[jj];
            for (int k = 0; k < 32; ++k) s += wh2_w[jj * 32 + k] * t1[k];
            t2[jj] = fmaxf(s, 0.f);
        }
        float rw[5], m = -1e30f;
#pragma unroll
        for (int o = 0; o < 5; ++o) {
            float s = wh3_b[o];
            for (int jj = 0; jj < 16; ++jj) s += wh3_w[o * 16 + jj] * t2[jj];
            rw[o] = s; m = fmaxf(m, s);
        }
        float se = 0.f;
#pragma unroll
        for (int o = 0; o < 5; ++o) { rw[o] = __expf(rw[o] - m); se += rw[o]; }
        float inv = 1.f / se, wp = 0.f;
#pragma unroll
        for (int o = 0; o < 5; ++o) {
            float w = rw[o] * inv;
            out[B_SZ + b * 5 + o] = w;
            wp += w * base_preds[b * 5 + o];
        }
        float rs = rh2_b[0];
#pragma unroll
        for (int k = 0; k < 16; ++k) rs += rh2_w[k] * r1[k];
        out[b] = fmaxf(wp + rs * 0.05f, 0.05f);
    }
}

extern "C" void kernel_launch(void* const* d_in, const int* in_sizes, int n_in,
                              void* d_out, int out_size, void* d_ws, size_t ws_size,
                              hipStream_t stream) {
    const float* node_feats = (const float*)d_in[0];
    const float* adj        = (const float*)d_in[1];
    const float* context    = (const float*)d_in[2];
    const float* base_preds = (const float*)d_in[3];
    const float* W1         = (const float*)d_in[4];
    const float* a1         = (const float*)d_in[5];
    const float* W2         = (const float*)d_in[6];
    const float* a2         = (const float*)d_in[7];
    const float* wh1_w = (const float*)d_in[8];
    const float* wh1_b = (const float*)d_in[9];
    const float* wh2_w = (const float*)d_in[10];
    const float* wh2_b = (const float*)d_in[11];
    const float* wh3_w = (const float*)d_in[12];
    const float* wh3_b = (const float*)d_in[13];
    const float* rh1_w = (const float*)d_in[14];
    const float* rh1_b = (const float*)d_in[15];
    const float* rh2_w = (const float*)d_in[16];
    const float* rh2_b = (const float*)d_in[17];
    float* out = (float*)d_out;

    us* W1b = (us*)d_ws;              // 131072 shorts
    us* W2b = W1b + 131072;           // 65536
    us* Whb = W2b + 65536;            // 98304 (wh1_w || rh1_w)

    pack_weights<<<288, 256, 0, stream>>>(W1, W2, wh1_w, rh1_w, W1b);

    fused_all<<<2048, 512, 0, stream>>>(node_feats, W1b, W2b, Whb, adj, a1, a2, context,
                                        wh1_b, wh2_w, wh2_b, wh3_w, wh3_b,
                                        rh1_b, rh2_w, rh2_b, base_preds, out);
}